// Round 1
// baseline (606.788 us; speedup 1.0000x reference)
//
#include <hip/hip_runtime.h>

#define BB 4096
#define NN 4096
#define DIM 16
#define RPB 2          // rows per block in k_K (LDS lut = RPB*16KB)
#define SEGS 32        // row segments in k_vpass
#define SEGROWS (BB / SEGS)

// ---------------- mean(D) reduction + vacc init ----------------
__global__ __launch_bounds__(256) void k_mean_init(
        const float* __restrict__ Dt, const float* __restrict__ cap,
        float* __restrict__ dsum, float* __restrict__ vacc) {
    const int tid = blockIdx.x * blockDim.x + threadIdx.x;
    if (tid < NN) vacc[tid] = cap[tid];   // seed so first vfinal yields v = 1
    const float4* D4 = (const float4*)Dt;
    const int total4 = (BB * NN) / 4;
    float s = 0.f;
    for (int i = tid; i < total4; i += gridDim.x * blockDim.x) {
        float4 d = D4[i];
        s += (d.x + d.y) + (d.z + d.w);
    }
    #pragma unroll
    for (int off = 32; off > 0; off >>= 1) s += __shfl_down(s, off, 64);
    __shared__ float ls[4];
    const int lane = threadIdx.x & 63, wave = threadIdx.x >> 6;
    if (lane == 0) ls[wave] = s;
    __syncthreads();
    if (threadIdx.x == 0) atomicAdd(dsum, (ls[0] + ls[1]) + (ls[2] + ls[3]));
}

// ---------------- K = exp(5*dot - 5*D/mean) ----------------
__global__ __launch_bounds__(256) void k_K(
        const int* __restrict__ users, const int* __restrict__ pois,
        const float* __restrict__ Dt, const float* __restrict__ poi_emb,
        const float* __restrict__ user_emb, const float* __restrict__ dsum,
        float* __restrict__ K) {
    __shared__ float s[RPB][NN];          // 2 * 16 KB lut
    __shared__ float ues[RPB][DIM];
    const int t = threadIdx.x;
    const int b0 = blockIdx.x * RPB;
    if (t < RPB * DIM) {
        int r = t / DIM, d = t % DIM;
        ues[r][d] = user_emb[(size_t)users[b0 + r] * DIM + d];
    }
    __syncthreads();
    float ue[RPB][DIM];
    #pragma unroll
    for (int r = 0; r < RPB; r++)
        #pragma unroll
        for (int d = 0; d < DIM; d++) ue[r][d] = ues[r][d];

    const float4* pe4 = (const float4*)poi_emb;   // row j = pe4[4j..4j+3]
    for (int j = t; j < NN; j += 256) {
        float4 p0 = pe4[j * 4 + 0];
        float4 p1 = pe4[j * 4 + 1];
        float4 p2 = pe4[j * 4 + 2];
        float4 p3 = pe4[j * 4 + 3];
        #pragma unroll
        for (int r = 0; r < RPB; r++) {
            float acc = p0.x*ue[r][0]  + p0.y*ue[r][1]  + p0.z*ue[r][2]  + p0.w*ue[r][3]
                      + p1.x*ue[r][4]  + p1.y*ue[r][5]  + p1.z*ue[r][6]  + p1.w*ue[r][7]
                      + p2.x*ue[r][8]  + p2.y*ue[r][9]  + p2.z*ue[r][10] + p2.w*ue[r][11]
                      + p3.x*ue[r][12] + p3.y*ue[r][13] + p3.z*ue[r][14] + p3.w*ue[r][15];
            s[r][j] = acc;
        }
    }
    __syncthreads();
    const float c = 5.0f * 16777216.0f / dsum[0];   // 5 / mean(D)
    #pragma unroll
    for (int r = 0; r < RPB; r++) {
        const size_t base = (size_t)(b0 + r) * NN;
        for (int n = t; n < NN; n += 256) {
            int idx = pois[base + n];
            float dv = Dt[base + n];
            K[base + n] = __expf(5.0f * s[r][idx] - c * dv);
        }
    }
}

// ---------------- v = cap / vacc ; vacc = 0 ----------------
__global__ void k_vfinal(const float* __restrict__ cap, float* __restrict__ vacc,
                         float* __restrict__ v) {
    int n = blockIdx.x * blockDim.x + threadIdx.x;
    if (n < NN) { v[n] = cap[n] / vacc[n]; vacc[n] = 0.f; }
}

// ---------------- u[b] = 1 / (K[b,:] . v) ----------------
__global__ __launch_bounds__(256) void k_upass(
        const float* __restrict__ K, const float* __restrict__ v,
        float* __restrict__ u) {
    const int b = blockIdx.x;
    const float4* K4 = (const float4*)(K + (size_t)b * NN);
    const float4* v4 = (const float4*)v;
    const int t = threadIdx.x;
    float s = 0.f;
    #pragma unroll
    for (int i = 0; i < 4; i++) {
        int j = i * 256 + t;
        float4 k = K4[j];
        float4 vv = v4[j];
        s += k.x * vv.x + k.y * vv.y + k.z * vv.z + k.w * vv.w;
    }
    #pragma unroll
    for (int off = 32; off > 0; off >>= 1) s += __shfl_down(s, off, 64);
    __shared__ float ls[4];
    if ((t & 63) == 0) ls[t >> 6] = s;
    __syncthreads();
    if (t == 0) u[b] = 1.0f / ((ls[0] + ls[1]) + (ls[2] + ls[3]));
}

// ---------------- vacc[n] += sum_seg K[b,n]*u[b] ----------------
__global__ __launch_bounds__(256) void k_vpass(
        const float* __restrict__ K, const float* __restrict__ u,
        float* __restrict__ vacc) {
    const int n = blockIdx.x * 256 + threadIdx.x;
    const int b0 = blockIdx.y * SEGROWS;
    const float* Kp = K + (size_t)b0 * NN + n;
    float acc = 0.f;
    #pragma unroll 4
    for (int i = 0; i < SEGROWS; i++)
        acc += Kp[(size_t)i * NN] * u[b0 + i];
    atomicAdd(&vacc[n], acc);
}

// ---------------- P = K * u[b] * v[n]  (in place over K) ----------------
__global__ __launch_bounds__(256) void k_P(
        float* __restrict__ K, const float* __restrict__ u,
        const float* __restrict__ v) {
    const int i = blockIdx.x * 256 + threadIdx.x;   // float4 index
    const int b = i >> 10;                           // NN/4 = 1024
    const int c4 = i & 1023;
    float ub = u[b];
    float4 k = ((const float4*)K)[i];
    float4 vv = ((const float4*)v)[c4];
    float4 p;
    p.x = k.x * ub * vv.x;
    p.y = k.y * ub * vv.y;
    p.z = k.z * ub * vv.z;
    p.w = k.w * ub * vv.w;
    ((float4*)K)[i] = p;
}

extern "C" void kernel_launch(void* const* d_in, const int* in_sizes, int n_in,
                              void* d_out, int out_size, void* d_ws, size_t ws_size,
                              hipStream_t stream) {
    const int*   users    = (const int*)d_in[0];
    const int*   pois     = (const int*)d_in[1];
    const float* Dt       = (const float*)d_in[2];
    const float* poi_emb  = (const float*)d_in[3];
    const float* user_emb = (const float*)d_in[4];
    const float* cap      = (const float*)d_in[5];
    float* K = (float*)d_out;          // K lives in d_out, overwritten by P
    float* wsf  = (float*)d_ws;
    float* dsum = wsf;                 // [1]
    float* u    = wsf + 1024;          // [BB]
    float* vacc = wsf + 1024 + BB;     // [NN]
    float* v    = wsf + 1024 + BB + NN;// [NN]

    hipMemsetAsync(dsum, 0, sizeof(float), stream);
    k_mean_init<<<2048, 256, 0, stream>>>(Dt, cap, dsum, vacc);
    k_K<<<BB / RPB, 256, 0, stream>>>(users, pois, Dt, poi_emb, user_emb, dsum, K);
    for (int it = 0; it < 10; it++) {
        k_vfinal<<<NN / 256, 256, 0, stream>>>(cap, vacc, v);
        k_upass<<<BB, 256, 0, stream>>>(K, v, u);
        k_vpass<<<dim3(NN / 256, SEGS), 256, 0, stream>>>(K, u, vacc);
    }
    k_vfinal<<<NN / 256, 256, 0, stream>>>(cap, vacc, v);
    k_P<<<(BB * NN / 4) / 256, 256, 0, stream>>>(K, u, v);
}

// Round 2
// 455.309 us; speedup vs baseline: 1.3327x; 1.3327x over previous
//
#include <hip/hip_runtime.h>
#include <hip/hip_fp16.h>

#define BB 4096
#define NN 4096
#define DIM 16
#define RPB 2                       // rows per block in k_K
#define ITERS 10
#define IBLOCKS 256                 // k_iter grid
#define ROWSPB (BB / IBLOCKS)       // 16 rows per k_iter block

// ---------------- mean(D) reduction + v=1, vacc=0 init ----------------
__global__ __launch_bounds__(256) void k_mean_init(
        const float* __restrict__ Dt, float* __restrict__ dsum,
        float* __restrict__ v, float* __restrict__ vacc) {
    const int tid = blockIdx.x * blockDim.x + threadIdx.x;
    if (tid < NN) { v[tid] = 1.0f; vacc[tid] = 0.0f; }
    const float4* D4 = (const float4*)Dt;
    const int total4 = (BB * NN) / 4;
    float s = 0.f;
    for (int i = tid; i < total4; i += gridDim.x * blockDim.x) {
        float4 d = D4[i];
        s += (d.x + d.y) + (d.z + d.w);
    }
    #pragma unroll
    for (int off = 32; off > 0; off >>= 1) s += __shfl_down(s, off, 64);
    __shared__ float ls[4];
    if ((threadIdx.x & 63) == 0) ls[threadIdx.x >> 6] = s;
    __syncthreads();
    if (threadIdx.x == 0) atomicAdd(dsum, (ls[0] + ls[1]) + (ls[2] + ls[3]));
}

// ---------------- K store helpers ----------------
__device__ inline void store4K(__half* p, float a, float b, float c, float d) {
    __half2* h2 = (__half2*)p;
    h2[0] = __floats2half2_rn(a, b);
    h2[1] = __floats2half2_rn(c, d);
}
__device__ inline void store4K(float* p, float a, float b, float c, float d) {
    *(float4*)p = make_float4(a, b, c, d);
}

// ---------------- K = exp(5*dot - 5*D/mean) ----------------
template<typename KT>
__global__ __launch_bounds__(256) void k_K(
        const int* __restrict__ users, const int* __restrict__ pois,
        const float* __restrict__ Dt, const float* __restrict__ poi_emb,
        const float* __restrict__ user_emb, const float* __restrict__ dsum,
        KT* __restrict__ K) {
    __shared__ float s[RPB][NN];          // 2 * 16 KB lut
    __shared__ float ues[RPB][DIM];
    const int t = threadIdx.x;
    const int b0 = blockIdx.x * RPB;
    if (t < RPB * DIM) {
        int r = t / DIM, d = t % DIM;
        ues[r][d] = user_emb[(size_t)users[b0 + r] * DIM + d];
    }
    __syncthreads();
    float ue[RPB][DIM];
    #pragma unroll
    for (int r = 0; r < RPB; r++)
        #pragma unroll
        for (int d = 0; d < DIM; d++) ue[r][d] = ues[r][d];

    const float4* pe4 = (const float4*)poi_emb;   // row j = pe4[4j..4j+3]
    for (int j = t; j < NN; j += 256) {
        float4 p0 = pe4[j * 4 + 0];
        float4 p1 = pe4[j * 4 + 1];
        float4 p2 = pe4[j * 4 + 2];
        float4 p3 = pe4[j * 4 + 3];
        #pragma unroll
        for (int r = 0; r < RPB; r++) {
            float acc = p0.x*ue[r][0]  + p0.y*ue[r][1]  + p0.z*ue[r][2]  + p0.w*ue[r][3]
                      + p1.x*ue[r][4]  + p1.y*ue[r][5]  + p1.z*ue[r][6]  + p1.w*ue[r][7]
                      + p2.x*ue[r][8]  + p2.y*ue[r][9]  + p2.z*ue[r][10] + p2.w*ue[r][11]
                      + p3.x*ue[r][12] + p3.y*ue[r][13] + p3.z*ue[r][14] + p3.w*ue[r][15];
            s[r][j] = acc;
        }
    }
    __syncthreads();
    const float c = 5.0f * 16777216.0f / dsum[0];   // 5 / mean(D)
    #pragma unroll
    for (int r = 0; r < RPB; r++) {
        const size_t base = (size_t)(b0 + r) * NN;
        const int4*   p4 = (const int4*)(pois + base);
        const float4* d4 = (const float4*)(Dt + base);
        for (int i = t; i < NN / 4; i += 256) {
            int4   idx = p4[i];
            float4 dv  = d4[i];
            float k0 = __expf(5.0f * s[r][idx.x] - c * dv.x);
            float k1 = __expf(5.0f * s[r][idx.y] - c * dv.y);
            float k2 = __expf(5.0f * s[r][idx.z] - c * dv.z);
            float k3 = __expf(5.0f * s[r][idx.w] - c * dv.w);
            store4K(K + base + 4 * (size_t)i, k0, k1, k2, k3);
        }
    }
}

// ---------------- row loads: 16 cols/thread ----------------
__device__ inline void loadrow16(const __half* __restrict__ Krow, int t, float out[16]) {
    const float4* K4 = (const float4*)Krow;
    float4 r0 = K4[t];          // halves 8t..8t+7
    float4 r1 = K4[256 + t];    // halves 2048+8t..
    const __half2* h0 = (const __half2*)&r0;
    const __half2* h1 = (const __half2*)&r1;
    #pragma unroll
    for (int i = 0; i < 4; i++) {
        float2 f = __half22float2(h0[i]);
        out[2*i] = f.x; out[2*i+1] = f.y;
    }
    #pragma unroll
    for (int i = 0; i < 4; i++) {
        float2 f = __half22float2(h1[i]);
        out[8+2*i] = f.x; out[8+2*i+1] = f.y;
    }
}
__device__ inline void loadrow16(const float* __restrict__ Krow, int t, float out[16]) {
    const float4* K4 = (const float4*)Krow;
    float4 r0 = K4[2*t], r1 = K4[2*t+1], r2 = K4[512+2*t], r3 = K4[512+2*t+1];
    out[0]=r0.x; out[1]=r0.y; out[2]=r0.z; out[3]=r0.w;
    out[4]=r1.x; out[5]=r1.y; out[6]=r1.z; out[7]=r1.w;
    out[8]=r2.x; out[9]=r2.y; out[10]=r2.z; out[11]=r2.w;
    out[12]=r3.x; out[13]=r3.y; out[14]=r3.z; out[15]=r3.w;
}

// ------- fused Sinkhorn iter: u[b]=1/(K[b,:].v) then acc[n]+=K[b,n]*u[b] -------
// thread t owns cols [8t..8t+7] and [2048+8t..2048+8t+7]
template<typename KT, bool USE_PART>
__global__ __launch_bounds__(256) void k_iter(
        const KT* __restrict__ K, const float* __restrict__ v,
        float* __restrict__ u, float* __restrict__ accout) {
    const int t = threadIdx.x;
    const int b0 = blockIdx.x * ROWSPB;
    float vr[16];
    {
        const float4* v4 = (const float4*)v;
        float4 a = v4[2*t], b = v4[2*t+1], c = v4[512+2*t], d = v4[512+2*t+1];
        vr[0]=a.x; vr[1]=a.y; vr[2]=a.z; vr[3]=a.w;
        vr[4]=b.x; vr[5]=b.y; vr[6]=b.z; vr[7]=b.w;
        vr[8]=c.x; vr[9]=c.y; vr[10]=c.z; vr[11]=c.w;
        vr[12]=d.x; vr[13]=d.y; vr[14]=d.z; vr[15]=d.w;
    }
    float acc[16];
    #pragma unroll
    for (int j = 0; j < 16; j++) acc[j] = 0.f;

    __shared__ float ls[2][4];
    float kv[16];
    loadrow16(K + (size_t)b0 * NN, t, kv);
    #pragma unroll 4
    for (int r = 0; r < ROWSPB; r++) {
        float kvn[16];
        if (r < ROWSPB - 1) loadrow16(K + (size_t)(b0 + r + 1) * NN, t, kvn);
        float p = 0.f;
        #pragma unroll
        for (int j = 0; j < 16; j++) p += kv[j] * vr[j];
        #pragma unroll
        for (int off = 32; off > 0; off >>= 1) p += __shfl_down(p, off, 64);
        const int par = r & 1;
        if ((t & 63) == 0) ls[par][t >> 6] = p;
        __syncthreads();
        float ub = 1.0f / ((ls[par][0] + ls[par][1]) + (ls[par][2] + ls[par][3]));
        if (t == 0) u[b0 + r] = ub;
        #pragma unroll
        for (int j = 0; j < 16; j++) acc[j] += ub * kv[j];
        #pragma unroll
        for (int j = 0; j < 16; j++) kv[j] = kvn[j];
    }
    if (USE_PART) {
        float4* P4 = (float4*)(accout + (size_t)blockIdx.x * NN);
        P4[2*t]       = make_float4(acc[0],  acc[1],  acc[2],  acc[3]);
        P4[2*t+1]     = make_float4(acc[4],  acc[5],  acc[6],  acc[7]);
        P4[512+2*t]   = make_float4(acc[8],  acc[9],  acc[10], acc[11]);
        P4[512+2*t+1] = make_float4(acc[12], acc[13], acc[14], acc[15]);
    } else {
        #pragma unroll
        for (int j = 0; j < 8; j++)  atomicAdd(&accout[8*t + j], acc[j]);
        #pragma unroll
        for (int j = 0; j < 8; j++)  atomicAdd(&accout[2048 + 8*t + j], acc[8 + j]);
    }
}

// ---------------- v finalize ----------------
// USE_PART: grid 64 blocks x 256; else grid 16 x 256
template<bool USE_PART>
__global__ __launch_bounds__(256) void k_vf(
        const float* __restrict__ cap, float* __restrict__ accin,
        float* __restrict__ v) {
    if (USE_PART) {
        const int l = threadIdx.x & 63;
        const int q = threadIdx.x >> 6;
        const int c = blockIdx.x * 64 + l;
        float s = 0.f;
        #pragma unroll 8
        for (int k = q; k < IBLOCKS; k += 4) s += accin[(size_t)k * NN + c];
        __shared__ float ls[4][64];
        ls[q][l] = s;
        __syncthreads();
        if (q == 0)
            v[c] = cap[c] / ((ls[0][l] + ls[1][l]) + (ls[2][l] + ls[3][l]));
    } else {
        const int n = blockIdx.x * 256 + threadIdx.x;
        v[n] = cap[n] / accin[n];
        accin[n] = 0.f;
    }
}

// ---------------- P = K * u[b] * v[n] ----------------
__global__ __launch_bounds__(256) void k_P_h(
        const __half* __restrict__ K, const float* __restrict__ u,
        const float* __restrict__ v, float* __restrict__ P) {
    const int i = blockIdx.x * 256 + threadIdx.x;  // half8 index
    const int e = i * 8;
    const int b = e >> 12;
    const int col = e & 4095;
    float4 raw = ((const float4*)K)[i];
    const __half2* h = (const __half2*)&raw;
    const float ub = u[b];
    float4 v0 = ((const float4*)v)[col >> 2];
    float4 v1 = ((const float4*)v)[(col >> 2) + 1];
    float2 f0 = __half22float2(h[0]);
    float2 f1 = __half22float2(h[1]);
    float2 f2 = __half22float2(h[2]);
    float2 f3 = __half22float2(h[3]);
    float4 o0 = make_float4(f0.x*ub*v0.x, f0.y*ub*v0.y, f1.x*ub*v0.z, f1.y*ub*v0.w);
    float4 o1 = make_float4(f2.x*ub*v1.x, f2.y*ub*v1.y, f3.x*ub*v1.z, f3.y*ub*v1.w);
    ((float4*)P)[e >> 2] = o0;
    ((float4*)P)[(e >> 2) + 1] = o1;
}
__global__ __launch_bounds__(256) void k_P_f(
        float* __restrict__ K, const float* __restrict__ u,
        const float* __restrict__ v) {
    const int i = blockIdx.x * 256 + threadIdx.x;   // float4 index
    const int b = i >> 10;
    const int c4 = i & 1023;
    float ub = u[b];
    float4 k = ((const float4*)K)[i];
    float4 vv = ((const float4*)v)[c4];
    ((float4*)K)[i] = make_float4(k.x*ub*vv.x, k.y*ub*vv.y, k.z*ub*vv.z, k.w*ub*vv.w);
}

extern "C" void kernel_launch(void* const* d_in, const int* in_sizes, int n_in,
                              void* d_out, int out_size, void* d_ws, size_t ws_size,
                              hipStream_t stream) {
    const int*   users    = (const int*)d_in[0];
    const int*   pois     = (const int*)d_in[1];
    const float* Dt       = (const float*)d_in[2];
    const float* poi_emb  = (const float*)d_in[3];
    const float* user_emb = (const float*)d_in[4];
    const float* cap      = (const float*)d_in[5];
    float* out = (float*)d_out;

    float* wsf  = (float*)d_ws;
    float* dsum = wsf;                         // [1]
    float* u    = wsf + 256;                   // [BB]
    float* v    = wsf + 256 + BB;              // [NN]
    float* vacc = wsf + 256 + BB + NN;         // [NN]
    float* part = wsf + 256 + BB + 2 * NN;     // [IBLOCKS*NN] = 4 MB
    __half* Kh  = (__half*)(part + (size_t)IBLOCKS * NN);

    const size_t smallBytes = (size_t)(256 + BB + 2 * NN) * 4;
    const size_t partBytes  = (size_t)IBLOCKS * NN * 4;
    const size_t khBytes    = (size_t)BB * NN * 2;
    const bool fp16path = ws_size >= smallBytes + partBytes + khBytes;
    const bool partpath = ws_size >= smallBytes + partBytes;

    hipMemsetAsync(dsum, 0, sizeof(float), stream);
    k_mean_init<<<2048, 256, 0, stream>>>(Dt, dsum, v, vacc);

    if (fp16path) {
        k_K<__half><<<BB / RPB, 256, 0, stream>>>(users, pois, Dt, poi_emb, user_emb, dsum, Kh);
        for (int it = 0; it < ITERS; it++) {
            k_iter<__half, true><<<IBLOCKS, 256, 0, stream>>>(Kh, v, u, part);
            k_vf<true><<<64, 256, 0, stream>>>(cap, part, v);
        }
        k_P_h<<<(BB * NN / 8) / 256, 256, 0, stream>>>(Kh, u, v, out);
    } else if (partpath) {
        float* Kf = out;
        k_K<float><<<BB / RPB, 256, 0, stream>>>(users, pois, Dt, poi_emb, user_emb, dsum, Kf);
        for (int it = 0; it < ITERS; it++) {
            k_iter<float, true><<<IBLOCKS, 256, 0, stream>>>(Kf, v, u, part);
            k_vf<true><<<64, 256, 0, stream>>>(cap, part, v);
        }
        k_P_f<<<(BB * NN / 4) / 256, 256, 0, stream>>>(Kf, u, v);
    } else {
        float* Kf = out;
        k_K<float><<<BB / RPB, 256, 0, stream>>>(users, pois, Dt, poi_emb, user_emb, dsum, Kf);
        for (int it = 0; it < ITERS; it++) {
            k_iter<float, false><<<IBLOCKS, 256, 0, stream>>>(Kf, v, u, vacc);
            k_vf<false><<<16, 256, 0, stream>>>(cap, vacc, v);
        }
        k_P_f<<<(BB * NN / 4) / 256, 256, 0, stream>>>(Kf, u, v);
    }
}